// Round 10
// baseline (378.866 us; speedup 1.0000x reference)
//
#include <hip/hip_runtime.h>
#include <math.h>

#define B_ 4
#define L_ 64
#define D_ 512
#define DI_ 1024
#define N_ 16
#define DC_ 4
#define R_ 32
#define NL_ 4
#define SD_ 17
#define AD_ 6
#define T_ 256    // 4*L
#define CH3_ 32   // scan chunks
#define TC3_ 8    // T_/CH3_
#define DL3_ 8    // d-lanes per group

// bf16 weight segment sizes (elements)
#define NW_IN  (NL_ * 2 * DI_ * D_)   // 4194304
#define NW_OUT (NL_ * D_ * DI_)       // 2097152
#define NW_XP  (NL_ * 64 * DI_)       // 262144
#define NW_TOT (NW_IN + NW_OUT + NW_XP)  // 6553600

typedef short bf16x8 __attribute__((ext_vector_type(8)));
typedef float f32x4 __attribute__((ext_vector_type(4)));

__device__ __forceinline__ float silu_f(float v) { return v / (1.f + __expf(-v)); }
__device__ __forceinline__ float softplus_f(float v) {
    return fmaxf(v, 0.f) + log1pf(__expf(-fabsf(v)));
}
__device__ __forceinline__ unsigned short f2bs(float f) {
    unsigned u = __float_as_uint(f);
    u += 0x7fffu + ((u >> 16) & 1u);
    return (unsigned short)(u >> 16);
}
__device__ __forceinline__ float bs2f(unsigned short s) {
    return __uint_as_float(((unsigned)s) << 16);
}

// ---------------------------------------------------------------------------
// One-time: weights fp32 -> bf16 (in_w | out_w | xp_w)
// ---------------------------------------------------------------------------
__global__ __launch_bounds__(256) void wcvt_kernel(
    const float* __restrict__ in_w, const float* __restrict__ out_w,
    const float* __restrict__ xp_w, unsigned short* __restrict__ wb)
{
    const int i = blockIdx.x * 256 + threadIdx.x;   // float4 index
    if (i >= NW_TOT / 4) return;
    const int e = i * 4;
    const float* src; int off;
    if (e < NW_IN)               { src = in_w;  off = e; }
    else if (e < NW_IN + NW_OUT) { src = out_w; off = e - NW_IN; }
    else                         { src = xp_w;  off = e - NW_IN - NW_OUT; }
    const float4 v = *(const float4*)(src + off);
    ushort4 o;
    o.x = f2bs(v.x); o.y = f2bs(v.y); o.z = f2bs(v.z); o.w = f2bs(v.w);
    *(ushort4*)(wb + e) = o;
}

// ---------------------------------------------------------------------------
// Embedding
// ---------------------------------------------------------------------------
__global__ __launch_bounds__(512) void embed_kernel(
    const float* __restrict__ states, const float* __restrict__ actions,
    const float* __restrict__ rtg, const float* __restrict__ ctg,
    const int* __restrict__ ts,
    const float* __restrict__ es_w, const float* __restrict__ es_b,
    const float* __restrict__ ea_w, const float* __restrict__ ea_b,
    const float* __restrict__ er_w, const float* __restrict__ er_b,
    const float* __restrict__ ec_w, const float* __restrict__ ec_b,
    const float* __restrict__ et_w, float* __restrict__ x)
{
    const int bl = blockIdx.x;
    const int d = threadIdx.x;
    const float te = et_w[(size_t)ts[bl] * D_ + d];
    const float r = rtg[bl] * er_w[d] + er_b[d] + te;
    const float c = ctg[bl] * ec_w[d] + ec_b[d] + te;
    float s = es_b[d] + te;
#pragma unroll
    for (int k = 0; k < SD_; ++k) s += states[bl * SD_ + k] * es_w[d * SD_ + k];
    float a = ea_b[d] + te;
#pragma unroll
    for (int k = 0; k < AD_; ++k) a += actions[bl * AD_ + k] * ea_w[d * AD_ + k];
    float* xp = x + (size_t)bl * 4 * D_;
    xp[0 * D_ + d] = r;
    xp[1 * D_ + d] = c;
    xp[2 * D_ + d] = s;
    xp[3 * D_ + d] = a;
}

// ---------------------------------------------------------------------------
// LayerNorm (+ residual sum of 4 split-K out_proj partials).
// MODE 0: ln(x) -> bf16.  MODE 1: x += p0..p3 (stored), ln -> bf16.
// MODE 2: x += p0..p3, ln -> fp32.
// ---------------------------------------------------------------------------
template <int MODE>
__global__ __launch_bounds__(256) void ln2_kernel(
    float* __restrict__ x, const float* __restrict__ p,
    const float* __restrict__ w, const float* __restrict__ b,
    void* __restrict__ o_)
{
    const int tok = blockIdx.x;
    const int tid = threadIdx.x;
    float2 v = reinterpret_cast<float2*>(x + (size_t)tok * D_)[tid];
    if (MODE >= 1) {
#pragma unroll
        for (int s4 = 0; s4 < 4; ++s4) {
            const float2 a = reinterpret_cast<const float2*>(
                p + (size_t)s4 * 524288 + (size_t)tok * D_)[tid];
            v.x += a.x; v.y += a.y;
        }
        reinterpret_cast<float2*>(x + (size_t)tok * D_)[tid] = v;
    }
    float s = v.x + v.y;
#pragma unroll
    for (int off = 1; off < 64; off <<= 1) s += __shfl_xor(s, off);
    __shared__ float red[8];
    const int wv = tid >> 6;
    if ((tid & 63) == 0) red[wv] = s;
    __syncthreads();
    const float mean = (red[0] + red[1] + red[2] + red[3]) * (1.f / D_);
    const float dx = v.x - mean, dy = v.y - mean;
    float q = dx * dx + dy * dy;
#pragma unroll
    for (int off = 1; off < 64; off <<= 1) q += __shfl_xor(q, off);
    if ((tid & 63) == 0) red[4 + wv] = q;
    __syncthreads();
    const float var = (red[4] + red[5] + red[6] + red[7]) * (1.f / D_);
    const float r = rsqrtf(var + 1e-5f);
    const int d0 = tid * 2;
    const float o0 = dx * r * w[d0] + b[d0];
    const float o1 = dy * r * w[d0 + 1] + b[d0 + 1];
    if (MODE == 2) {
        float* o = (float*)o_;
        o[(size_t)tok * D_ + d0] = o0;
        o[(size_t)tok * D_ + d0 + 1] = o1;
    } else {
        unsigned short* o = (unsigned short*)o_;
        o[(size_t)tok * D_ + d0] = f2bs(o0);
        o[(size_t)tok * D_ + d0 + 1] = f2bs(o1);
    }
}

// ---------------------------------------------------------------------------
// MFMA bf16 GEMM, A and W both bf16, K compile-time.
// EPI 3: in_proj split store (col<DI -> xmb bf16; col>=DI -> zs=silu bf16)
// EPI 4: split-K partial store to C + blockIdx.z*(1024*512), k base z*KT
// ---------------------------------------------------------------------------
template <int MR, int NR, int EPI, int KT>
__global__ __launch_bounds__(256) void gemm3(
    const unsigned short* __restrict__ A, int lda,
    const unsigned short* __restrict__ W, int ldw,
    float* __restrict__ C, unsigned short* __restrict__ Cb1,
    unsigned short* __restrict__ Cb2, int N)
{
    const int lane = threadIdx.x & 63, wid = threadIdx.x >> 6;
    const int r = lane & 15, kq = lane >> 4;
    const int wm = blockIdx.y * (2 * MR * 16) + (wid >> 1) * (MR * 16);
    const int wn = blockIdx.x * (2 * NR * 16) + (wid & 1) * (NR * 16);
    const int kb = (EPI == 4) ? blockIdx.z * KT : 0;
    f32x4 acc[MR][NR] = {};
#pragma unroll 4
    for (int k0 = 0; k0 < KT; k0 += 32) {
        bf16x8 a[MR], b[NR];
#pragma unroll
        for (int i = 0; i < MR; ++i)
            a[i] = *(const bf16x8*)(A + (size_t)(wm + i * 16 + r) * lda + kb + k0 + kq * 8);
#pragma unroll
        for (int j = 0; j < NR; ++j)
            b[j] = *(const bf16x8*)(W + (size_t)(wn + j * 16 + r) * ldw + kb + k0 + kq * 8);
#pragma unroll
        for (int i = 0; i < MR; ++i)
#pragma unroll
            for (int j = 0; j < NR; ++j)
                acc[i][j] = __builtin_amdgcn_mfma_f32_16x16x32_bf16(a[i], b[j], acc[i][j], 0, 0, 0);
    }
    // C/D layout: col = lane&15, row = (lane>>4)*4 + reg
#pragma unroll
    for (int i = 0; i < MR; ++i)
#pragma unroll
        for (int j = 0; j < NR; ++j)
#pragma unroll
            for (int g = 0; g < 4; ++g) {
                const int row = wm + i * 16 + kq * 4 + g;
                const int col = wn + j * 16 + r;
                const float val = acc[i][j][g];
                if (EPI == 3) {
                    if (col < DI_) Cb1[(size_t)row * DI_ + col] = f2bs(val);
                    else Cb2[(size_t)row * DI_ + (col - DI_)] = f2bs(silu_f(val));
                } else if (EPI == 4) {
                    C[(size_t)blockIdx.z * (1024 * 512) + (size_t)row * 512 + col] = val;
                } else {
                    C[(size_t)row * N + col] = val;
                }
            }
}

// ---------------------------------------------------------------------------
// Fused conv1d+silu + xp GEMM v2 — 4x more blocks.
// Grid (4, 64): block (nq, mt) owns 16 rows x 16-col slice of dbc.
// Phase A: conv+silu for its 16 rows x 1024 d -> swizzled LDS (duplicated
// across the 4 nq blocks — cheap VALU; xcb written only by nq==0).
// Phase B: 16x16x1024 GEMM, 4-wave split-K (256 each), LDS reduce.
// ---------------------------------------------------------------------------
__global__ __launch_bounds__(256) void convxp_kernel(
    const unsigned short* __restrict__ xmb, const float* __restrict__ cw,
    const float* __restrict__ cb, const unsigned short* __restrict__ Wb,
    unsigned short* __restrict__ xcb, float* __restrict__ dbc)
{
    __shared__ unsigned short sA[16 * 1024];   // 32 KB, swizzled
    __shared__ float red[4][16][16];           // 4 KB
    const int tid = threadIdx.x;
    const int nq = blockIdx.x;          // 0..3: 16-col slice
    const int m0 = blockIdx.y * 16;
    // --- Phase A: conv + silu ---
    for (int task = tid; task < 16 * 128; task += 256) {
        const int rr = task >> 7;           // 0..15
        const int dd0 = (task & 127) * 8;   // 0..1016
        const int row = m0 + rr;
        const int t = row & (T_ - 1);
        float4 cw4[8];
#pragma unroll
        for (int j = 0; j < 8; ++j) cw4[j] = ((const float4*)cw)[dd0 + j];
        float acc[8];
#pragma unroll
        for (int j = 0; j < 8; ++j) acc[j] = cb[dd0 + j];
#pragma unroll
        for (int k = 0; k < DC_; ++k) {
            if (t - 3 + k >= 0) {
                const bf16x8 v = *(const bf16x8*)(xmb + (size_t)(row - 3 + k) * DI_ + dd0);
#pragma unroll
                for (int j = 0; j < 8; ++j) {
                    const float wk = (k == 0) ? cw4[j].x : (k == 1) ? cw4[j].y
                                   : (k == 2) ? cw4[j].z : cw4[j].w;
                    acc[j] += wk * bs2f((unsigned short)v[j]);
                }
            }
        }
        bf16x8 ov;
#pragma unroll
        for (int j = 0; j < 8; ++j) ov[j] = (short)f2bs(silu_f(acc[j]));
        if (nq == 0)
            *(bf16x8*)(xcb + (size_t)row * DI_ + dd0) = ov;
        const int byteoff = (rr * 2048 + dd0 * 2) ^ ((rr & 7) << 4);
        *(bf16x8*)((char*)sA + byteoff) = ov;
    }
    __syncthreads();
    // --- Phase B: 16 x 16 GEMM slice, 4-way split-K over waves ---
    const int wid = tid >> 6, lane = tid & 63;
    const int r = lane & 15, kq = lane >> 4;
    f32x4 acc4 = {};
    const int k00 = wid * 256;
#pragma unroll
    for (int ks = 0; ks < 8; ++ks) {
        const int k0 = k00 + ks * 32;
        const int abyte = (r * 2048 + (k0 + kq * 8) * 2) ^ ((r & 7) << 4);
        const bf16x8 a = *(const bf16x8*)((const char*)sA + abyte);
        const bf16x8 bfr = *(const bf16x8*)(Wb + (size_t)(nq * 16 + r) * DI_ + k0 + kq * 8);
        acc4 = __builtin_amdgcn_mfma_f32_16x16x32_bf16(a, bfr, acc4, 0, 0, 0);
    }
#pragma unroll
    for (int g = 0; g < 4; ++g)
        red[wid][kq * 4 + g][r] = acc4[g];
    __syncthreads();
    if (tid < 256) {
        const int row = tid >> 4, col = tid & 15;
        const float s = red[0][row][col] + red[1][row][col] +
                        red[2][row][col] + red[3][row][col];
        dbc[(size_t)(m0 + row) * 64 + nq * 16 + col] = s;
    }
}

// ---------------------------------------------------------------------------
// Fused selective scan (unchanged from R9).
// ---------------------------------------------------------------------------
__global__ __launch_bounds__(256, 3) void scan_kernel(
    const unsigned short* __restrict__ xcb, const float* __restrict__ dbc,
    const float* __restrict__ dtw, const float* __restrict__ dtbias,
    const float* __restrict__ A_log, const float* __restrict__ Dp,
    const unsigned short* __restrict__ zs, unsigned short* __restrict__ ygb)
{
    __shared__ float dlt_s[T_][DL3_ + 1];
    __shared__ float Sl[CH3_][DL3_][17];
    __shared__ float Pl[CH3_][DL3_][17];
    const int tid = threadIdx.x;
    const int dl = tid & (DL3_ - 1);
    const int c = tid >> 3;
    const int b = blockIdx.x >> 7;
    const int d = (blockIdx.x & 127) * DL3_ + dl;
    const int row0 = b * T_ + c * TC3_;
    {
        const float4* Wp = (const float4*)(dtw + (size_t)d * R_);
        float4 w4[8];
#pragma unroll
        for (int q = 0; q < 8; ++q) w4[q] = Wp[q];
        const float bias = dtbias[d];
#pragma unroll
        for (int t = 0; t < TC3_; ++t) {
            const float4* Ap = (const float4*)(dbc + (size_t)(row0 + t) * 64);
            float acc = bias;
#pragma unroll
            for (int q = 0; q < 8; ++q) {
                const float4 a4 = Ap[q];
                acc += a4.x * w4[q].x + a4.y * w4[q].y + a4.z * w4[q].z + a4.w * w4[q].w;
            }
            dlt_s[c * TC3_ + t][dl] = softplus_f(acc);
        }
    }
    float Av[N_];
    {
        const float4* Alp = (const float4*)(A_log + (size_t)d * N_);
#pragma unroll
        for (int q = 0; q < 4; ++q) {
            const float4 v = Alp[q];
            Av[q * 4 + 0] = -__expf(v.x);
            Av[q * 4 + 1] = -__expf(v.y);
            Av[q * 4 + 2] = -__expf(v.z);
            Av[q * 4 + 3] = -__expf(v.w);
        }
    }
    __syncthreads();
    const unsigned short* up = xcb + (size_t)row0 * DI_ + d;
    const float* bc = dbc + (size_t)row0 * 64;
    float h[N_];
#pragma unroll
    for (int n = 0; n < N_; ++n) h[n] = 0.f;
    float dsum = 0.f;
#pragma unroll
    for (int t = 0; t < TC3_; ++t) {
        const float dt_t = dlt_s[c * TC3_ + t][dl];
        dsum += dt_t;
        const float dbu = dt_t * bs2f(up[t * DI_]);
#pragma unroll
        for (int q = 0; q < 4; ++q) {
            const float4 b4 = *(const float4*)(bc + t * 64 + R_ + q * 4);
            h[q * 4 + 0] = __expf(dt_t * Av[q * 4 + 0]) * h[q * 4 + 0] + dbu * b4.x;
            h[q * 4 + 1] = __expf(dt_t * Av[q * 4 + 1]) * h[q * 4 + 1] + dbu * b4.y;
            h[q * 4 + 2] = __expf(dt_t * Av[q * 4 + 2]) * h[q * 4 + 2] + dbu * b4.z;
            h[q * 4 + 3] = __expf(dt_t * Av[q * 4 + 3]) * h[q * 4 + 3] + dbu * b4.w;
        }
    }
#pragma unroll
    for (int n = 0; n < N_; ++n) {
        Sl[c][dl][n] = h[n];
        Pl[c][dl][n] = __expf(Av[n] * dsum);
    }
    __syncthreads();
    if (tid < DL3_ * N_) {
        const int dd = tid >> 4, nn = tid & 15;
        float hin = 0.f;
#pragma unroll
        for (int c2 = 0; c2 < CH3_; ++c2) {
            const float t2 = Pl[c2][dd][nn] * hin + Sl[c2][dd][nn];
            Sl[c2][dd][nn] = hin;
            hin = t2;
        }
    }
    __syncthreads();
#pragma unroll
    for (int n = 0; n < N_; ++n) h[n] = Sl[c][dl][n];
    const float Dd = Dp[d];
    const unsigned short* zp = zs + (size_t)row0 * DI_ + d;
    unsigned short* yp = ygb + (size_t)row0 * DI_ + d;
#pragma unroll
    for (int t = 0; t < TC3_; ++t) {
        const float dt_t = dlt_s[c * TC3_ + t][dl];
        const float ut = bs2f(up[t * DI_]);
        const float dbu = dt_t * ut;
        float y = ut * Dd;
#pragma unroll
        for (int q = 0; q < 4; ++q) {
            const float4 b4 = *(const float4*)(bc + t * 64 + R_ + q * 4);
            const float4 c4 = *(const float4*)(bc + t * 64 + R_ + N_ + q * 4);
            h[q * 4 + 0] = __expf(dt_t * Av[q * 4 + 0]) * h[q * 4 + 0] + dbu * b4.x;
            h[q * 4 + 1] = __expf(dt_t * Av[q * 4 + 1]) * h[q * 4 + 1] + dbu * b4.y;
            h[q * 4 + 2] = __expf(dt_t * Av[q * 4 + 2]) * h[q * 4 + 2] + dbu * b4.z;
            h[q * 4 + 3] = __expf(dt_t * Av[q * 4 + 3]) * h[q * 4 + 3] + dbu * b4.w;
            y += h[q * 4 + 0] * c4.x + h[q * 4 + 1] * c4.y
               + h[q * 4 + 2] * c4.z + h[q * 4 + 3] * c4.w;
        }
        yp[t * DI_] = f2bs(y * bs2f(zp[t * DI_]));
    }
}

// ---------------------------------------------------------------------------
// Heads
// ---------------------------------------------------------------------------
__global__ __launch_bounds__(256) void heads_kernel(
    const float* __restrict__ xn,
    const float* __restrict__ ps_w, const float* __restrict__ ps_b,
    const float* __restrict__ pa_w, const float* __restrict__ pa_b,
    float* __restrict__ out)
{
    const int idx = blockIdx.x * 4 + (threadIdx.x >> 6);
    const int lane = threadIdx.x & 63;
    const int bl = idx / 23, j = idx % 23;
    const float* tok;
    const float* wrow;
    float bias;
    float* dst;
    if (j < SD_) {
        tok = xn + ((size_t)bl * 4 + 3) * D_;
        wrow = ps_w + (size_t)j * D_;
        bias = ps_b[j];
        dst = out + (size_t)bl * SD_ + j;
    } else {
        const int jj = j - SD_;
        tok = xn + ((size_t)bl * 4 + 2) * D_;
        wrow = pa_w + (size_t)jj * D_;
        bias = pa_b[jj];
        dst = out + (size_t)B_ * L_ * SD_ + (size_t)bl * AD_ + jj;
    }
    float s = 0.f;
    for (int dd = lane; dd < D_; dd += 64) s += tok[dd] * wrow[dd];
#pragma unroll
    for (int off = 1; off < 64; off <<= 1) s += __shfl_xor(s, off);
    if (lane == 0) *dst = s + bias;
}

// ---------------------------------------------------------------------------
extern "C" void kernel_launch(void* const* d_in, const int* in_sizes, int n_in,
                              void* d_out, int out_size, void* d_ws, size_t ws_size,
                              hipStream_t stream)
{
    const float* states  = (const float*)d_in[0];
    const float* actions = (const float*)d_in[1];
    const float* rtg     = (const float*)d_in[2];
    const float* ctg     = (const float*)d_in[3];
    const int*   ts      = (const int*)d_in[4];
    const float* es_w = (const float*)d_in[5];  const float* es_b = (const float*)d_in[6];
    const float* ea_w = (const float*)d_in[7];  const float* ea_b = (const float*)d_in[8];
    const float* er_w = (const float*)d_in[9];  const float* er_b = (const float*)d_in[10];
    const float* ec_w = (const float*)d_in[11]; const float* ec_b = (const float*)d_in[12];
    const float* et_w = (const float*)d_in[13];
    const float* ln_w = (const float*)d_in[14]; const float* ln_b = (const float*)d_in[15];
    const float* in_w = (const float*)d_in[16];
    const float* conv_w = (const float*)d_in[17]; const float* conv_b = (const float*)d_in[18];
    const float* xp_w = (const float*)d_in[19];
    const float* dtp_w = (const float*)d_in[20]; const float* dtp_b = (const float*)d_in[21];
    const float* A_log = (const float*)d_in[22]; const float* Dp = (const float*)d_in[23];
    const float* out_w = (const float*)d_in[24];
    const float* fn_w = (const float*)d_in[25]; const float* fn_b = (const float*)d_in[26];
    const float* ps_w = (const float*)d_in[27]; const float* ps_b = (const float*)d_in[28];
    const float* pa_w = (const float*)d_in[29]; const float* pa_b = (const float*)d_in[30];
    float* out = (float*)d_out;

    // workspace layout
    float* ws   = (float*)d_ws;
    float* x    = ws;                    // 524288 f32
    float* xn   = x + 524288;            // 524288 f32 (final LN out)
    float* p    = xn + 524288;           // 2097152 f32 (out_proj partials p0..p3)
    float* dbc  = p + 2097152;           // 65536 f32
    unsigned short* xnb = (unsigned short*)(dbc + 65536);  // 524288 bf16
    unsigned short* xmb = xnb + 524288;                    // 1048576 bf16
    unsigned short* xcb = xmb + 1048576;                   // 1048576 bf16
    unsigned short* zs  = xcb + 1048576;                   // 1048576 bf16
    unsigned short* ygb = zs + 1048576;                    // 1048576 bf16
    unsigned short* wb  = ygb + 1048576;                   // 6553600 bf16
    unsigned short* wb_in  = wb;
    unsigned short* wb_out = wb + NW_IN;
    unsigned short* wb_xp  = wb + NW_IN + NW_OUT;

    wcvt_kernel<<<(NW_TOT / 4 + 255) / 256, 256, 0, stream>>>(in_w, out_w, xp_w, wb);
    embed_kernel<<<B_ * L_, D_, 0, stream>>>(states, actions, rtg, ctg, ts,
        es_w, es_b, ea_w, ea_b, er_w, er_b, ec_w, ec_b, et_w, x);

    for (int i = 0; i < NL_; ++i) {
        if (i == 0)
            ln2_kernel<0><<<B_ * T_, 256, 0, stream>>>(
                x, nullptr, ln_w, ln_b, xnb);
        else
            ln2_kernel<1><<<B_ * T_, 256, 0, stream>>>(
                x, p, ln_w + i * D_, ln_b + i * D_, xnb);
        // in_proj: (1024 x 2048 x 512), 32x64 tiles -> 1024 blocks
        gemm3<1, 2, 3, 512><<<dim3(32, 32), 256, 0, stream>>>(
            xnb, D_, wb_in + (size_t)i * 2 * DI_ * D_, D_, nullptr, xmb, zs, 2 * DI_);
        // conv+silu fused with xp GEMM -> xcb bf16, dbc fp32 (256 blocks)
        convxp_kernel<<<dim3(4, 64), 256, 0, stream>>>(
            xmb, conv_w + i * DI_ * DC_, conv_b + i * DI_,
            wb_xp + (size_t)i * 64 * DI_, xcb, dbc);
        // fused delta + chunked scan + gate -> ygb bf16 (512 blocks)
        scan_kernel<<<B_ * (DI_ / DL3_), 256, 0, stream>>>(
            xcb, dbc, dtp_w + (size_t)i * DI_ * R_, dtp_b + i * DI_,
            A_log + (size_t)i * DI_ * N_, Dp + i * DI_, zs, ygb);
        // out_proj split-K=4: 32x64 tiles, K=256/slice -> 1024 blocks
        gemm3<1, 2, 4, 256><<<dim3(8, 32, 4), 256, 0, stream>>>(
            ygb, DI_, wb_out + (size_t)i * D_ * DI_, DI_, p, nullptr, nullptr, D_);
    }

    ln2_kernel<2><<<B_ * T_, 256, 0, stream>>>(x, p, fn_w, fn_b, xn);
    heads_kernel<<<(B_ * L_ * 23) / 4, 256, 0, stream>>>(xn, ps_w, ps_b, pa_w, pa_b, out);
}

// Round 11
// 289.166 us; speedup vs baseline: 1.3102x; 1.3102x over previous
//
#include <hip/hip_runtime.h>
#include <math.h>

#define B_ 4
#define L_ 64
#define D_ 512
#define DI_ 1024
#define N_ 16
#define DC_ 4
#define R_ 32
#define NL_ 4
#define SD_ 17
#define AD_ 6
#define T_ 256    // 4*L
#define CH3_ 32   // scan chunks
#define TC3_ 8    // T_/CH3_
#define DL3_ 8    // d-lanes per group

// bf16 weight segment sizes (elements)
#define NW_IN  (NL_ * 2 * DI_ * D_)   // 4194304
#define NW_OUT (NL_ * D_ * DI_)       // 2097152
#define NW_XP  (NL_ * 64 * DI_)       // 262144
#define NW_TOT (NW_IN + NW_OUT + NW_XP)  // 6553600

typedef short bf16x8 __attribute__((ext_vector_type(8)));
typedef float f32x4 __attribute__((ext_vector_type(4)));

__device__ __forceinline__ float silu_f(float v) { return v / (1.f + __expf(-v)); }
__device__ __forceinline__ float softplus_f(float v) {
    return fmaxf(v, 0.f) + log1pf(__expf(-fabsf(v)));
}
__device__ __forceinline__ unsigned short f2bs(float f) {
    unsigned u = __float_as_uint(f);
    u += 0x7fffu + ((u >> 16) & 1u);
    return (unsigned short)(u >> 16);
}
__device__ __forceinline__ float bs2f(unsigned short s) {
    return __uint_as_float(((unsigned)s) << 16);
}

// ---------------------------------------------------------------------------
// One-time: weights fp32 -> bf16 (in_w | out_w | xp_w)
// ---------------------------------------------------------------------------
__global__ __launch_bounds__(256) void wcvt_kernel(
    const float* __restrict__ in_w, const float* __restrict__ out_w,
    const float* __restrict__ xp_w, unsigned short* __restrict__ wb)
{
    const int i = blockIdx.x * 256 + threadIdx.x;   // float4 index
    if (i >= NW_TOT / 4) return;
    const int e = i * 4;
    const float* src; int off;
    if (e < NW_IN)               { src = in_w;  off = e; }
    else if (e < NW_IN + NW_OUT) { src = out_w; off = e - NW_IN; }
    else                         { src = xp_w;  off = e - NW_IN - NW_OUT; }
    const float4 v = *(const float4*)(src + off);
    ushort4 o;
    o.x = f2bs(v.x); o.y = f2bs(v.y); o.z = f2bs(v.z); o.w = f2bs(v.w);
    *(ushort4*)(wb + e) = o;
}

// ---------------------------------------------------------------------------
// Embedding
// ---------------------------------------------------------------------------
__global__ __launch_bounds__(512) void embed_kernel(
    const float* __restrict__ states, const float* __restrict__ actions,
    const float* __restrict__ rtg, const float* __restrict__ ctg,
    const int* __restrict__ ts,
    const float* __restrict__ es_w, const float* __restrict__ es_b,
    const float* __restrict__ ea_w, const float* __restrict__ ea_b,
    const float* __restrict__ er_w, const float* __restrict__ er_b,
    const float* __restrict__ ec_w, const float* __restrict__ ec_b,
    const float* __restrict__ et_w, float* __restrict__ x)
{
    const int bl = blockIdx.x;
    const int d = threadIdx.x;
    const float te = et_w[(size_t)ts[bl] * D_ + d];
    const float r = rtg[bl] * er_w[d] + er_b[d] + te;
    const float c = ctg[bl] * ec_w[d] + ec_b[d] + te;
    float s = es_b[d] + te;
#pragma unroll
    for (int k = 0; k < SD_; ++k) s += states[bl * SD_ + k] * es_w[d * SD_ + k];
    float a = ea_b[d] + te;
#pragma unroll
    for (int k = 0; k < AD_; ++k) a += actions[bl * AD_ + k] * ea_w[d * AD_ + k];
    float* xp = x + (size_t)bl * 4 * D_;
    xp[0 * D_ + d] = r;
    xp[1 * D_ + d] = c;
    xp[2 * D_ + d] = s;
    xp[3 * D_ + d] = a;
}

// ---------------------------------------------------------------------------
// LayerNorm (+ optional residual partial sum from split-K out_proj).
// MODE 0: ln(x) -> bf16 out.  MODE 1: x += p0+p1 (stored), ln -> bf16 out.
// MODE 2: x += p0+p1, ln -> fp32 out.
// ---------------------------------------------------------------------------
template <int MODE>
__global__ __launch_bounds__(256) void ln2_kernel(
    float* __restrict__ x, const float* __restrict__ p0,
    const float* __restrict__ p1,
    const float* __restrict__ w, const float* __restrict__ b,
    void* __restrict__ o_)
{
    const int tok = blockIdx.x;
    const int tid = threadIdx.x;
    float2 v = reinterpret_cast<float2*>(x + (size_t)tok * D_)[tid];
    if (MODE >= 1) {
        const float2 a0 = reinterpret_cast<const float2*>(p0 + (size_t)tok * D_)[tid];
        const float2 a1 = reinterpret_cast<const float2*>(p1 + (size_t)tok * D_)[tid];
        v.x += a0.x + a1.x;
        v.y += a0.y + a1.y;
        reinterpret_cast<float2*>(x + (size_t)tok * D_)[tid] = v;
    }
    float s = v.x + v.y;
#pragma unroll
    for (int off = 1; off < 64; off <<= 1) s += __shfl_xor(s, off);
    __shared__ float red[8];
    const int wv = tid >> 6;
    if ((tid & 63) == 0) red[wv] = s;
    __syncthreads();
    const float mean = (red[0] + red[1] + red[2] + red[3]) * (1.f / D_);
    const float dx = v.x - mean, dy = v.y - mean;
    float q = dx * dx + dy * dy;
#pragma unroll
    for (int off = 1; off < 64; off <<= 1) q += __shfl_xor(q, off);
    if ((tid & 63) == 0) red[4 + wv] = q;
    __syncthreads();
    const float var = (red[4] + red[5] + red[6] + red[7]) * (1.f / D_);
    const float r = rsqrtf(var + 1e-5f);
    const int d0 = tid * 2;
    const float o0 = dx * r * w[d0] + b[d0];
    const float o1 = dy * r * w[d0 + 1] + b[d0 + 1];
    if (MODE == 2) {
        float* o = (float*)o_;
        o[(size_t)tok * D_ + d0] = o0;
        o[(size_t)tok * D_ + d0 + 1] = o1;
    } else {
        unsigned short* o = (unsigned short*)o_;
        o[(size_t)tok * D_ + d0] = f2bs(o0);
        o[(size_t)tok * D_ + d0 + 1] = f2bs(o1);
    }
}

// ---------------------------------------------------------------------------
// MFMA bf16 GEMM, A and W both bf16, K compile-time.
// EPI 3: in_proj split store (col<DI -> xmb bf16; col>=DI -> zs=silu bf16)
// EPI 4: split-K partial store to C + blockIdx.z*(1024*512), k base z*KT
// ---------------------------------------------------------------------------
template <int MR, int NR, int EPI, int KT>
__global__ __launch_bounds__(256) void gemm3(
    const unsigned short* __restrict__ A, int lda,
    const unsigned short* __restrict__ W, int ldw,
    float* __restrict__ C, unsigned short* __restrict__ Cb1,
    unsigned short* __restrict__ Cb2, int N)
{
    const int lane = threadIdx.x & 63, wid = threadIdx.x >> 6;
    const int r = lane & 15, kq = lane >> 4;
    const int wm = blockIdx.y * (2 * MR * 16) + (wid >> 1) * (MR * 16);
    const int wn = blockIdx.x * (2 * NR * 16) + (wid & 1) * (NR * 16);
    const int kb = (EPI == 4) ? blockIdx.z * KT : 0;
    f32x4 acc[MR][NR] = {};
#pragma unroll 4
    for (int k0 = 0; k0 < KT; k0 += 32) {
        bf16x8 a[MR], b[NR];
#pragma unroll
        for (int i = 0; i < MR; ++i)
            a[i] = *(const bf16x8*)(A + (size_t)(wm + i * 16 + r) * lda + kb + k0 + kq * 8);
#pragma unroll
        for (int j = 0; j < NR; ++j)
            b[j] = *(const bf16x8*)(W + (size_t)(wn + j * 16 + r) * ldw + kb + k0 + kq * 8);
#pragma unroll
        for (int i = 0; i < MR; ++i)
#pragma unroll
            for (int j = 0; j < NR; ++j)
                acc[i][j] = __builtin_amdgcn_mfma_f32_16x16x32_bf16(a[i], b[j], acc[i][j], 0, 0, 0);
    }
    // C/D layout: col = lane&15, row = (lane>>4)*4 + reg
#pragma unroll
    for (int i = 0; i < MR; ++i)
#pragma unroll
        for (int j = 0; j < NR; ++j)
#pragma unroll
            for (int g = 0; g < 4; ++g) {
                const int row = wm + i * 16 + kq * 4 + g;
                const int col = wn + j * 16 + r;
                const float val = acc[i][j][g];
                if (EPI == 3) {
                    if (col < DI_) Cb1[(size_t)row * DI_ + col] = f2bs(val);
                    else Cb2[(size_t)row * DI_ + (col - DI_)] = f2bs(silu_f(val));
                } else if (EPI == 4) {
                    C[(size_t)blockIdx.z * (1024 * 512) + (size_t)row * 512 + col] = val;
                } else {
                    C[(size_t)row * N + col] = val;
                }
            }
}

// ---------------------------------------------------------------------------
// Causal depthwise conv1d (DC=4) + SiLU, bf16 in/out. De-fused from convxp
// (R10 lesson: conv is the expensive phase; at 64 blocks it serialized on
// 1/4 of the CUs, and duplicating it 4x regressed). 512 blocks, 8 d/thread,
// fully coalesced 16B/lane.
// ---------------------------------------------------------------------------
__global__ __launch_bounds__(256) void conv_kernel(
    const unsigned short* __restrict__ xmb, const float* __restrict__ cw,
    const float* __restrict__ cb, unsigned short* __restrict__ xcb)
{
    const int e0 = (blockIdx.x * 256 + threadIdx.x) * 8;   // element base
    const int d0 = e0 & (DI_ - 1);
    const int bt = e0 >> 10;            // row = b*T + t
    const int t = bt & (T_ - 1);
    float4 w4[8];
#pragma unroll
    for (int j = 0; j < 8; ++j) w4[j] = ((const float4*)cw)[d0 + j];
    float acc[8];
#pragma unroll
    for (int j = 0; j < 8; ++j) acc[j] = cb[d0 + j];
#pragma unroll
    for (int k = 0; k < DC_; ++k) {
        if (t - 3 + k >= 0) {
            const bf16x8 v = *(const bf16x8*)(xmb + (size_t)(bt - 3 + k) * DI_ + d0);
#pragma unroll
            for (int j = 0; j < 8; ++j) {
                const float wk = (k == 0) ? w4[j].x : (k == 1) ? w4[j].y
                               : (k == 2) ? w4[j].z : w4[j].w;
                acc[j] += wk * bs2f((unsigned short)v[j]);
            }
        }
    }
    bf16x8 ov;
#pragma unroll
    for (int j = 0; j < 8; ++j) ov[j] = (short)f2bs(silu_f(acc[j]));
    *(bf16x8*)(xcb + e0) = ov;
}

// ---------------------------------------------------------------------------
// xp GEMM: dbc[1024,64] = xcb @ xp_w^T, 64 blocks (16 rows each),
// 4-wave in-block split-K (256 each) + LDS reduce. ~0.13 GF — tiny.
// ---------------------------------------------------------------------------
__global__ __launch_bounds__(256) void xp_kernel(
    const unsigned short* __restrict__ xcb, const unsigned short* __restrict__ Wb,
    float* __restrict__ dbc)
{
    __shared__ float red[4][16][64];
    const int tid = threadIdx.x;
    const int wid = tid >> 6, lane = tid & 63;
    const int r = lane & 15, kq = lane >> 4;
    const int m0 = blockIdx.x * 16;
    f32x4 acc4[4] = {};
    const int k00 = wid * 256;
#pragma unroll
    for (int ks = 0; ks < 8; ++ks) {
        const int k0 = k00 + ks * 32;
        const bf16x8 a = *(const bf16x8*)(xcb + (size_t)(m0 + r) * DI_ + k0 + kq * 8);
#pragma unroll
        for (int j = 0; j < 4; ++j) {
            const bf16x8 bfr = *(const bf16x8*)(Wb + (size_t)(j * 16 + r) * DI_ + k0 + kq * 8);
            acc4[j] = __builtin_amdgcn_mfma_f32_16x16x32_bf16(a, bfr, acc4[j], 0, 0, 0);
        }
    }
#pragma unroll
    for (int j = 0; j < 4; ++j)
#pragma unroll
        for (int g = 0; g < 4; ++g)
            red[wid][kq * 4 + g][j * 16 + r] = acc4[j][g];
    __syncthreads();
    for (int i = tid; i < 1024; i += 256) {
        const int row = i >> 6, col = i & 63;
        const float s = red[0][row][col] + red[1][row][col] +
                        red[2][row][col] + red[3][row][col];
        dbc[(size_t)(m0 + row) * 64 + col] = s;
    }
}

// ---------------------------------------------------------------------------
// Fused selective scan (unchanged from R9).
// ---------------------------------------------------------------------------
__global__ __launch_bounds__(256, 3) void scan_kernel(
    const unsigned short* __restrict__ xcb, const float* __restrict__ dbc,
    const float* __restrict__ dtw, const float* __restrict__ dtbias,
    const float* __restrict__ A_log, const float* __restrict__ Dp,
    const unsigned short* __restrict__ zs, unsigned short* __restrict__ ygb)
{
    __shared__ float dlt_s[T_][DL3_ + 1];
    __shared__ float Sl[CH3_][DL3_][17];
    __shared__ float Pl[CH3_][DL3_][17];
    const int tid = threadIdx.x;
    const int dl = tid & (DL3_ - 1);
    const int c = tid >> 3;
    const int b = blockIdx.x >> 7;
    const int d = (blockIdx.x & 127) * DL3_ + dl;
    const int row0 = b * T_ + c * TC3_;
    {
        const float4* Wp = (const float4*)(dtw + (size_t)d * R_);
        float4 w4[8];
#pragma unroll
        for (int q = 0; q < 8; ++q) w4[q] = Wp[q];
        const float bias = dtbias[d];
#pragma unroll
        for (int t = 0; t < TC3_; ++t) {
            const float4* Ap = (const float4*)(dbc + (size_t)(row0 + t) * 64);
            float acc = bias;
#pragma unroll
            for (int q = 0; q < 8; ++q) {
                const float4 a4 = Ap[q];
                acc += a4.x * w4[q].x + a4.y * w4[q].y + a4.z * w4[q].z + a4.w * w4[q].w;
            }
            dlt_s[c * TC3_ + t][dl] = softplus_f(acc);
        }
    }
    float Av[N_];
    {
        const float4* Alp = (const float4*)(A_log + (size_t)d * N_);
#pragma unroll
        for (int q = 0; q < 4; ++q) {
            const float4 v = Alp[q];
            Av[q * 4 + 0] = -__expf(v.x);
            Av[q * 4 + 1] = -__expf(v.y);
            Av[q * 4 + 2] = -__expf(v.z);
            Av[q * 4 + 3] = -__expf(v.w);
        }
    }
    __syncthreads();
    const unsigned short* up = xcb + (size_t)row0 * DI_ + d;
    const float* bc = dbc + (size_t)row0 * 64;
    float h[N_];
#pragma unroll
    for (int n = 0; n < N_; ++n) h[n] = 0.f;
    float dsum = 0.f;
#pragma unroll
    for (int t = 0; t < TC3_; ++t) {
        const float dt_t = dlt_s[c * TC3_ + t][dl];
        dsum += dt_t;
        const float dbu = dt_t * bs2f(up[t * DI_]);
#pragma unroll
        for (int q = 0; q < 4; ++q) {
            const float4 b4 = *(const float4*)(bc + t * 64 + R_ + q * 4);
            h[q * 4 + 0] = __expf(dt_t * Av[q * 4 + 0]) * h[q * 4 + 0] + dbu * b4.x;
            h[q * 4 + 1] = __expf(dt_t * Av[q * 4 + 1]) * h[q * 4 + 1] + dbu * b4.y;
            h[q * 4 + 2] = __expf(dt_t * Av[q * 4 + 2]) * h[q * 4 + 2] + dbu * b4.z;
            h[q * 4 + 3] = __expf(dt_t * Av[q * 4 + 3]) * h[q * 4 + 3] + dbu * b4.w;
        }
    }
#pragma unroll
    for (int n = 0; n < N_; ++n) {
        Sl[c][dl][n] = h[n];
        Pl[c][dl][n] = __expf(Av[n] * dsum);
    }
    __syncthreads();
    if (tid < DL3_ * N_) {
        const int dd = tid >> 4, nn = tid & 15;
        float hin = 0.f;
#pragma unroll
        for (int c2 = 0; c2 < CH3_; ++c2) {
            const float t2 = Pl[c2][dd][nn] * hin + Sl[c2][dd][nn];
            Sl[c2][dd][nn] = hin;
            hin = t2;
        }
    }
    __syncthreads();
#pragma unroll
    for (int n = 0; n < N_; ++n) h[n] = Sl[c][dl][n];
    const float Dd = Dp[d];
    const unsigned short* zp = zs + (size_t)row0 * DI_ + d;
    unsigned short* yp = ygb + (size_t)row0 * DI_ + d;
#pragma unroll
    for (int t = 0; t < TC3_; ++t) {
        const float dt_t = dlt_s[c * TC3_ + t][dl];
        const float ut = bs2f(up[t * DI_]);
        const float dbu = dt_t * ut;
        float y = ut * Dd;
#pragma unroll
        for (int q = 0; q < 4; ++q) {
            const float4 b4 = *(const float4*)(bc + t * 64 + R_ + q * 4);
            const float4 c4 = *(const float4*)(bc + t * 64 + R_ + N_ + q * 4);
            h[q * 4 + 0] = __expf(dt_t * Av[q * 4 + 0]) * h[q * 4 + 0] + dbu * b4.x;
            h[q * 4 + 1] = __expf(dt_t * Av[q * 4 + 1]) * h[q * 4 + 1] + dbu * b4.y;
            h[q * 4 + 2] = __expf(dt_t * Av[q * 4 + 2]) * h[q * 4 + 2] + dbu * b4.z;
            h[q * 4 + 3] = __expf(dt_t * Av[q * 4 + 3]) * h[q * 4 + 3] + dbu * b4.w;
            y += h[q * 4 + 0] * c4.x + h[q * 4 + 1] * c4.y
               + h[q * 4 + 2] * c4.z + h[q * 4 + 3] * c4.w;
        }
        yp[t * DI_] = f2bs(y * bs2f(zp[t * DI_]));
    }
}

// ---------------------------------------------------------------------------
// Heads
// ---------------------------------------------------------------------------
__global__ __launch_bounds__(256) void heads_kernel(
    const float* __restrict__ xn,
    const float* __restrict__ ps_w, const float* __restrict__ ps_b,
    const float* __restrict__ pa_w, const float* __restrict__ pa_b,
    float* __restrict__ out)
{
    const int idx = blockIdx.x * 4 + (threadIdx.x >> 6);
    const int lane = threadIdx.x & 63;
    const int bl = idx / 23, j = idx % 23;
    const float* tok;
    const float* wrow;
    float bias;
    float* dst;
    if (j < SD_) {
        tok = xn + ((size_t)bl * 4 + 3) * D_;
        wrow = ps_w + (size_t)j * D_;
        bias = ps_b[j];
        dst = out + (size_t)bl * SD_ + j;
    } else {
        const int jj = j - SD_;
        tok = xn + ((size_t)bl * 4 + 2) * D_;
        wrow = pa_w + (size_t)jj * D_;
        bias = pa_b[jj];
        dst = out + (size_t)B_ * L_ * SD_ + (size_t)bl * AD_ + jj;
    }
    float s = 0.f;
    for (int dd = lane; dd < D_; dd += 64) s += tok[dd] * wrow[dd];
#pragma unroll
    for (int off = 1; off < 64; off <<= 1) s += __shfl_xor(s, off);
    if (lane == 0) *dst = s + bias;
}

// ---------------------------------------------------------------------------
extern "C" void kernel_launch(void* const* d_in, const int* in_sizes, int n_in,
                              void* d_out, int out_size, void* d_ws, size_t ws_size,
                              hipStream_t stream)
{
    const float* states  = (const float*)d_in[0];
    const float* actions = (const float*)d_in[1];
    const float* rtg     = (const float*)d_in[2];
    const float* ctg     = (const float*)d_in[3];
    const int*   ts      = (const int*)d_in[4];
    const float* es_w = (const float*)d_in[5];  const float* es_b = (const float*)d_in[6];
    const float* ea_w = (const float*)d_in[7];  const float* ea_b = (const float*)d_in[8];
    const float* er_w = (const float*)d_in[9];  const float* er_b = (const float*)d_in[10];
    const float* ec_w = (const float*)d_in[11]; const float* ec_b = (const float*)d_in[12];
    const float* et_w = (const float*)d_in[13];
    const float* ln_w = (const float*)d_in[14]; const float* ln_b = (const float*)d_in[15];
    const float* in_w = (const float*)d_in[16];
    const float* conv_w = (const float*)d_in[17]; const float* conv_b = (const float*)d_in[18];
    const float* xp_w = (const float*)d_in[19];
    const float* dtp_w = (const float*)d_in[20]; const float* dtp_b = (const float*)d_in[21];
    const float* A_log = (const float*)d_in[22]; const float* Dp = (const float*)d_in[23];
    const float* out_w = (const float*)d_in[24];
    const float* fn_w = (const float*)d_in[25]; const float* fn_b = (const float*)d_in[26];
    const float* ps_w = (const float*)d_in[27]; const float* ps_b = (const float*)d_in[28];
    const float* pa_w = (const float*)d_in[29]; const float* pa_b = (const float*)d_in[30];
    float* out = (float*)d_out;

    // workspace layout
    float* ws   = (float*)d_ws;
    float* x    = ws;                    // 524288 f32
    float* xn   = x + 524288;            // 524288 f32 (final LN out)
    float* p    = xn + 524288;           // 1048576 f32 (out_proj partials p0|p1)
    float* dbc  = p + 1048576;           // 65536 f32
    unsigned short* xnb = (unsigned short*)(dbc + 65536);  // 524288 bf16
    unsigned short* xmb = xnb + 524288;                    // 1048576 bf16
    unsigned short* xcb = xmb + 1048576;                   // 1048576 bf16
    unsigned short* zs  = xcb + 1048576;                   // 1048576 bf16
    unsigned short* ygb = zs + 1048576;                    // 1048576 bf16
    unsigned short* wb  = ygb + 1048576;                   // 6553600 bf16
    unsigned short* wb_in  = wb;
    unsigned short* wb_out = wb + NW_IN;
    unsigned short* wb_xp  = wb + NW_IN + NW_OUT;

    wcvt_kernel<<<(NW_TOT / 4 + 255) / 256, 256, 0, stream>>>(in_w, out_w, xp_w, wb);
    embed_kernel<<<B_ * L_, D_, 0, stream>>>(states, actions, rtg, ctg, ts,
        es_w, es_b, ea_w, ea_b, er_w, er_b, ec_w, ec_b, et_w, x);

    for (int i = 0; i < NL_; ++i) {
        if (i == 0)
            ln2_kernel<0><<<B_ * T_, 256, 0, stream>>>(
                x, nullptr, nullptr, ln_w, ln_b, xnb);
        else
            ln2_kernel<1><<<B_ * T_, 256, 0, stream>>>(
                x, p, p + 524288, ln_w + i * D_, ln_b + i * D_, xnb);
        // in_proj: (1024 x 2048 x 512) -> xmb bf16 | zs=silu(z) bf16
        gemm3<2, 2, 3, 512><<<dim3(32, 16), 256, 0, stream>>>(
            xnb, D_, wb_in + (size_t)i * 2 * DI_ * D_, D_, nullptr, xmb, zs, 2 * DI_);
        // conv+silu -> xcb (512 blocks, all CUs)
        conv_kernel<<<512, 256, 0, stream>>>(
            xmb, conv_w + i * DI_ * DC_, conv_b + i * DI_, xcb);
        // xp GEMM -> dbc (tiny)
        xp_kernel<<<64, 256, 0, stream>>>(
            xcb, wb_xp + (size_t)i * 64 * DI_, dbc);
        // fused delta + chunked scan + gate -> ygb bf16 (512 blocks)
        scan_kernel<<<B_ * (DI_ / DL3_), 256, 0, stream>>>(
            xcb, dbc, dtp_w + (size_t)i * DI_ * R_, dtp_b + i * DI_,
            A_log + (size_t)i * DI_ * N_, Dp + i * DI_, zs, ygb);
        // out_proj split-K=2: p[z] = yg[:, z*512:+512] @ W[:, z*512:+512]^T
        gemm3<2, 2, 4, 512><<<dim3(8, 16, 2), 256, 0, stream>>>(
            ygb, DI_, wb_out + (size_t)i * D_ * DI_, DI_, p, nullptr, nullptr, D_);
    }

    ln2_kernel<2><<<B_ * T_, 256, 0, stream>>>(x, p, p + 524288, fn_w, fn_b, xn);
    heads_kernel<<<(B_ * L_ * 23) / 4, 256, 0, stream>>>(xn, ps_w, ps_b, pa_w, pa_b, out);
}